// Round 3
// baseline (276.178 us; speedup 1.0000x reference)
//
#include <hip/hip_runtime.h>

#define NN 50000
#define NE 600000
#define DD 128
#define NG 64

typedef unsigned int uint;
typedef unsigned short ushort;
typedef __attribute__((ext_vector_type(8))) short short8;
typedef __attribute__((ext_vector_type(4))) float f4;

// ---------------- bf16 helpers ----------------

__device__ __forceinline__ float bf_lo(uint v) { return __uint_as_float(v << 16); }
__device__ __forceinline__ float bf_hi(uint v) { return __uint_as_float(v & 0xffff0000u); }
__device__ __forceinline__ float bf2f(ushort h) { return __uint_as_float((uint)h << 16); }
__device__ __forceinline__ ushort f2bf(float f) {
    uint u = __float_as_uint(f);
    uint r = (u + 0x7fffu + ((u >> 16) & 1u)) >> 16;   // round-nearest-even
    return (ushort)r;
}

// ---------------- setup kernels ----------------

// blocks [0,2344): degree histogram; ALSO records each edge's rank within its
// dst (the atomicAdd return) so the CSR scatter needs no atomic.
// blocks [2344,2368): pack W (split bf16 hi/lo into MFMA B-fragment layout).
__global__ void k_hist_wpack(const int* __restrict__ dstv, int* __restrict__ deg,
                             int* __restrict__ rank,
                             const float* __restrict__ W1, const float* __restrict__ W2,
                             const float* __restrict__ W3, short* __restrict__ wpk) {
    if (blockIdx.x < 2344) {
        int e = blockIdx.x * 256 + threadIdx.x;
        if (e < NE) rank[e] = atomicAdd(&deg[dstv[e]], 1);
    } else {
        int u = (blockIdx.x - 2344) * 256 + threadIdx.x;   // < 6144
        int layer = u >> 11, g = u & 2047;
        const float* W = (layer == 0) ? W1 : (layer == 1) ? W2 : W3;
        short* base = wpk + (size_t)layer * 32768;
        int nt = g >> 8, kk = (g >> 6) & 3, lane = g & 63;
        int k0 = kk * 32 + (lane >> 4) * 8;
        int n = nt * 16 + (lane & 15);
        #pragma unroll
        for (int j = 0; j < 8; ++j) {
            float w = W[(size_t)(k0 + j) * DD + n];
            ushort h = f2bf(w);
            base[g * 8 + j] = (short)h;
            base[16384 + g * 8 + j] = (short)f2bf(w - bf2f(h));
        }
    }
}

// Rows padded to multiples of 8 (pad cols -> zero row NN). rp is over PADDED
// sizes; dinv over true size (deg+1 incl self-loop).
__global__ void k_scan1(const int* __restrict__ deg, float* __restrict__ dinv,
                        int* __restrict__ rp, int* __restrict__ bsum) {
    __shared__ int s[256];
    int t = threadIdx.x, i = blockIdx.x * 256 + t;
    int ts = (i < NN) ? (deg[i] + 1) : 0;
    int vp = (i < NN) ? ((ts + 7) & ~7) : 0;
    if (i < NN) dinv[i] = rsqrtf((float)ts);
    s[t] = vp; __syncthreads();
    for (int off = 1; off < 256; off <<= 1) {
        int x = (t >= off) ? s[t - off] : 0;
        __syncthreads();
        s[t] += x;
        __syncthreads();
    }
    if (i < NN) rp[i] = s[t] - vp;          // exclusive (padded)
    if (t == 255) bsum[blockIdx.x] = s[255];
}

// fused scan2+scan3 + pad-slot fill + self-loop write + hsT zero-row init.
__global__ void k_scan23(int* __restrict__ rp, const int* __restrict__ bs,
                         const int* __restrict__ deg, ushort* __restrict__ col,
                         ushort* __restrict__ hsT) {
    __shared__ int s[256];
    int t = threadIdx.x;
    int v = (t < 196) ? bs[t] : 0;
    s[t] = v; __syncthreads();
    for (int off = 1; off < 256; off <<= 1) {
        int x = (t >= off) ? s[t - off] : 0;
        __syncthreads();
        s[t] += x;
        __syncthreads();
    }
    __shared__ int ps[256];
    ps[t] = s[t] - v;                        // exclusive
    __syncthreads();
    int add = ps[blockIdx.x];
    int i = blockIdx.x * 256 + t;
    if (i < NN) {
        int rpi = rp[i] + add;
        rp[i] = rpi;
        int ts = deg[i] + 1;
        int P = (ts + 7) & ~7;
        col[rpi] = (ushort)i;                // self-loop in slot 0, no atomic
        for (int j = ts; j < P; ++j) col[rpi + j] = (ushort)NN;  // pads -> zero row
    }
    if (blockIdx.x == 0) {
        if (t == 255) rp[NN] = s[255];       // total padded size
        if (t < 64) ((uint*)(hsT + (size_t)NN * DD))[t] = 0;   // zero row
    }
}

// XCD-localized CSR scatter (see round-2 notes: avoids cross-XCD random-line
// writeback amplification; 39.7 MB -> ~3 MB of HBM writes).
__global__ __launch_bounds__(256) void k_scatter_xcd(const int* __restrict__ srcv,
                                                     const int* __restrict__ dstv,
                                                     const int* __restrict__ rank,
                                                     const int* __restrict__ rp,
                                                     ushort* __restrict__ col) {
    const int r8 = blockIdx.x & 7;
    const int chunk = blockIdx.x >> 3;
    const int lo = r8 * (NN / 8), hi = lo + (NN / 8);
    int e0 = chunk * 1024 + threadIdx.x * 4;
    if (e0 >= NE) return;                    // NE % 4 == 0: int4 loads in-bounds
    int4 d4 = *(const int4*)&dstv[e0];
    int4 s4 = *(const int4*)&srcv[e0];
    int4 k4 = *(const int4*)&rank[e0];
    const int* dp = (const int*)&d4;
    const int* sp = (const int*)&s4;
    const int* kp = (const int*)&k4;
    #pragma unroll
    for (int j = 0; j < 4; ++j) {
        int d = dp[j];
        if (d >= lo && d < hi)
            col[rp[d] + 1 + kp[j]] = (ushort)sp[j];   // slot 0 = self-loop
    }
}

// ---------------- MFMA GEMM ----------------
// out[r][c] = bf16( (X[r][:] @ W[:][c]) * dinv[r] )
// N split across blockIdx.y (2 halves of 64 cols); 32 KB LDS for W frags,
// reused post-barrier to stage C for coalesced float4 stores.
#define CST 72   // C-stage LDS row stride in shorts
template <int INF32>
__global__ __launch_bounds__(256) void k_gemm_mfma(const void* __restrict__ Xv,
                                                   const short* __restrict__ wpk,
                                                   const float* __restrict__ dinv,
                                                   ushort* __restrict__ out) {
    __shared__ short lds[16384];   // W: hi [0,8192), lo [8192,16384); C-stage reuse
    const int t = threadIdx.x;
    const int yb = blockIdx.y * 8192;
    #pragma unroll
    for (int m = 0; m < 4; ++m) {
        int idx = (m * 256 + t) * 8;
        *(float4*)&lds[idx] = *(const float4*)&wpk[yb + idx];
        *(float4*)&lds[8192 + idx] = *(const float4*)&wpk[16384 + yb + idx];
    }

    const int wv = t >> 6, lane = t & 63;
    const int quad = lane >> 4, l16 = lane & 15;
    const int r0 = blockIdx.x * 128 + wv * 32;

    short8 aH[2][4], aL[2][4];
    #pragma unroll
    for (int s = 0; s < 2; ++s) {
        int row = r0 + s * 16 + l16;
        #pragma unroll
        for (int kk = 0; kk < 4; ++kk) {
            int koff = kk * 32 + quad * 8;
            if (INF32) {
                float4 x0 = make_float4(0.f, 0.f, 0.f, 0.f), x1 = x0;
                if (row < NN) {
                    const float* p = (const float*)Xv + (size_t)row * DD + koff;
                    x0 = *(const float4*)p; x1 = *(const float4*)(p + 4);
                }
                float xs[8] = {x0.x, x0.y, x0.z, x0.w, x1.x, x1.y, x1.z, x1.w};
                short8 h, l;
                #pragma unroll
                for (int j = 0; j < 8; ++j) {
                    ushort hb = f2bf(xs[j]);
                    h[j] = (short)hb;
                    l[j] = (short)f2bf(xs[j] - bf2f(hb));
                }
                aH[s][kk] = h; aL[s][kk] = l;
            } else {
                short8 h = {0, 0, 0, 0, 0, 0, 0, 0};
                if (row < NN)
                    h = *(const short8*)((const ushort*)Xv + (size_t)row * DD + koff);
                aH[s][kk] = h;
            }
        }
    }
    __syncthreads();

    float dv[2][4];
    #pragma unroll
    for (int s = 0; s < 2; ++s)
        #pragma unroll
        for (int i = 0; i < 4; ++i) {
            int row = r0 + s * 16 + quad * 4 + i;
            dv[s][i] = (row < NN) ? dinv[row] : 0.f;
        }

    f4 acc[2][4];
    #pragma unroll
    for (int s = 0; s < 2; ++s)
        #pragma unroll
        for (int nt = 0; nt < 4; ++nt)
            acc[s][nt] = (f4){0.f, 0.f, 0.f, 0.f};

    #pragma unroll
    for (int nt = 0; nt < 4; ++nt) {
        #pragma unroll
        for (int kk = 0; kk < 4; ++kk) {
            int fi = ((nt * 4 + kk) * 64 + lane) * 8;
            short8 bh = *(const short8*)&lds[fi];
            short8 bl = *(const short8*)&lds[8192 + fi];
            acc[0][nt] = __builtin_amdgcn_mfma_f32_16x16x32_bf16(aH[0][kk], bh, acc[0][nt], 0, 0, 0);
            acc[0][nt] = __builtin_amdgcn_mfma_f32_16x16x32_bf16(aH[0][kk], bl, acc[0][nt], 0, 0, 0);
            acc[1][nt] = __builtin_amdgcn_mfma_f32_16x16x32_bf16(aH[1][kk], bh, acc[1][nt], 0, 0, 0);
            acc[1][nt] = __builtin_amdgcn_mfma_f32_16x16x32_bf16(aH[1][kk], bl, acc[1][nt], 0, 0, 0);
            if (INF32) {
                acc[0][nt] = __builtin_amdgcn_mfma_f32_16x16x32_bf16(aL[0][kk], bh, acc[0][nt], 0, 0, 0);
                acc[1][nt] = __builtin_amdgcn_mfma_f32_16x16x32_bf16(aL[1][kk], bh, acc[1][nt], 0, 0, 0);
            }
        }
    }

    __syncthreads();   // reuse LDS for C stage
    #pragma unroll
    for (int s = 0; s < 2; ++s) {
        int lr = wv * 32 + s * 16 + quad * 4;
        #pragma unroll
        for (int nt = 0; nt < 4; ++nt)
            #pragma unroll
            for (int i = 0; i < 4; ++i)
                lds[(lr + i) * CST + nt * 16 + l16] = (short)f2bf(acc[s][nt][i] * dv[s][i]);
    }
    __syncthreads();

    int row = t >> 1, half = t & 1;
    int grow = blockIdx.x * 128 + row;
    if (grow < NN) {
        #pragma unroll
        for (int j = 0; j < 4; ++j) {
            float4 v = *(float4*)&lds[row * CST + half * 32 + j * 8];
            *(float4*)&out[(size_t)grow * DD + blockIdx.y * 64 + half * 32 + j * 8] = v;
        }
    }
}

// ---------------- aggregation ----------------
// out[i] = maybe_relu( dinv[i] * sum_{p in row i} hs[col[p]] + bias )
// Wave per node. Lane split: l16 = lane&15 owns 8 dims (16 B of the row),
// g16 = lane>>4 picks one of 4 neighbors -> one dwordx4 gather covers 4 rows
// per wave-instruction. Per 8 neighbors: 1 broadcast 16 B col load + 2
// dwordx4 gathers (3 vmem instrs vs 9 in the dword version). col load for the
// next iteration is issued before this iteration's gathers (latency hidden).
// Epilogue: butterfly shfl_xor(16,32) over the 8 partials; lanes 0-15 write.
template <int RELU, int OUTF32>
__global__ __launch_bounds__(256) void k_agg(const ushort* __restrict__ hs,
                                             const ushort* __restrict__ col,
                                             const int* __restrict__ rp,
                                             const float* __restrict__ dinv,
                                             const float* __restrict__ bias,
                                             void* __restrict__ outv) {
    int w = threadIdx.x >> 6, lane = threadIdx.x & 63;
    int i = blockIdx.x * 4 + w;
    if (i >= NN) return;
    int p0 = rp[i], p1 = rp[i + 1];          // both multiples of 8
    const int g16 = lane >> 4, l16 = lane & 15;
    const uint* hsu = (const uint*)hs + (l16 << 2);   // lane's 16 B slice base

    float a0 = 0.f, a1 = 0.f, a2 = 0.f, a3 = 0.f;
    float a4 = 0.f, a5 = 0.f, a6 = 0.f, a7 = 0.f;

    short8 cv = *(const short8*)&col[p0];
    for (int p = p0; p < p1; p += 8) {
        int cA = (ushort)cv[g16];
        int cB = (ushort)cv[g16 + 4];
        // prefetch next col vector (unconditional: worst case reads 16 B into
        // the adjacent wpk allocation, value never consumed)
        cv = *(const short8*)&col[p + 8];
        uint4 vA = *(const uint4*)(hsu + ((size_t)cA << 6));
        uint4 vB = *(const uint4*)(hsu + ((size_t)cB << 6));
        a0 += bf_lo(vA.x); a1 += bf_hi(vA.x); a2 += bf_lo(vA.y); a3 += bf_hi(vA.y);
        a4 += bf_lo(vA.z); a5 += bf_hi(vA.z); a6 += bf_lo(vA.w); a7 += bf_hi(vA.w);
        a0 += bf_lo(vB.x); a1 += bf_hi(vB.x); a2 += bf_lo(vB.y); a3 += bf_hi(vB.y);
        a4 += bf_lo(vB.z); a5 += bf_hi(vB.z); a6 += bf_lo(vB.w); a7 += bf_hi(vB.w);
    }

    // reduce the 4 neighbor-groups (lanes l16, l16+16, l16+32, l16+48)
    a0 += __shfl_xor(a0, 16); a1 += __shfl_xor(a1, 16);
    a2 += __shfl_xor(a2, 16); a3 += __shfl_xor(a3, 16);
    a4 += __shfl_xor(a4, 16); a5 += __shfl_xor(a5, 16);
    a6 += __shfl_xor(a6, 16); a7 += __shfl_xor(a7, 16);
    a0 += __shfl_xor(a0, 32); a1 += __shfl_xor(a1, 32);
    a2 += __shfl_xor(a2, 32); a3 += __shfl_xor(a3, 32);
    a4 += __shfl_xor(a4, 32); a5 += __shfl_xor(a5, 32);
    a6 += __shfl_xor(a6, 32); a7 += __shfl_xor(a7, 32);

    if (g16 == 0) {
        float s = dinv[i];
        float4 bA = *(const float4*)(bias + l16 * 8);
        float4 bB = *(const float4*)(bias + l16 * 8 + 4);
        float o0 = fmaf(s, a0, bA.x), o1 = fmaf(s, a1, bA.y);
        float o2 = fmaf(s, a2, bA.z), o3 = fmaf(s, a3, bA.w);
        float o4 = fmaf(s, a4, bB.x), o5 = fmaf(s, a5, bB.y);
        float o6 = fmaf(s, a6, bB.z), o7 = fmaf(s, a7, bB.w);
        if (RELU) {
            o0 = fmaxf(o0, 0.f); o1 = fmaxf(o1, 0.f); o2 = fmaxf(o2, 0.f); o3 = fmaxf(o3, 0.f);
            o4 = fmaxf(o4, 0.f); o5 = fmaxf(o5, 0.f); o6 = fmaxf(o6, 0.f); o7 = fmaxf(o7, 0.f);
        }
        if (OUTF32) {
            float* op = (float*)outv + (size_t)i * DD + l16 * 8;
            *(float4*)op = make_float4(o0, o1, o2, o3);
            *(float4*)(op + 4) = make_float4(o4, o5, o6, o7);
        } else {
            short8 o;
            o[0] = (short)f2bf(o0); o[1] = (short)f2bf(o1);
            o[2] = (short)f2bf(o2); o[3] = (short)f2bf(o3);
            o[4] = (short)f2bf(o4); o[5] = (short)f2bf(o5);
            o[6] = (short)f2bf(o6); o[7] = (short)f2bf(o7);
            *(short8*)((ushort*)outv + (size_t)i * DD + l16 * 8) = o;
        }
    }
}

// ---------------- pool ----------------
// batch sorted: 782 blocks x 128 dims, run-length accumulate per 64-node
// chunk, one atomicAdd per (graph transition, dim).
__global__ __launch_bounds__(128) void k_pool(const float* __restrict__ h,
                                              const int* __restrict__ batch,
                                              float* __restrict__ sums,
                                              float* __restrict__ cnt) {
    int d = threadIdx.x;  // 0..127
    int start = blockIdx.x * 64;
    if (start >= NN) return;
    int end = min(start + 64, NN);
    float acc = 0.f, c = 0.f;
    int g = batch[start];
    for (int i = start; i < end; ++i) {
        int gi = batch[i];
        if (gi != g) {
            atomicAdd(&sums[g * DD + d], acc);
            if (d == 0) atomicAdd(&cnt[g], c);
            acc = 0.f; c = 0.f; g = gi;
        }
        acc += h[(size_t)i * DD + d];
        c += 1.f;
    }
    atomicAdd(&sums[g * DD + d], acc);
    if (d == 0) atomicAdd(&cnt[g], c);
}

__global__ void k_final(const float* __restrict__ sums, const float* __restrict__ cnt,
                        float* __restrict__ out) {
    int i = blockIdx.x * 256 + threadIdx.x;  // < NG*DD = 8192
    int g = i >> 7;
    out[i] = sums[i] / fmaxf(cnt[g], 1.f);
}

// ---------------- launch ----------------

extern "C" void kernel_launch(void* const* d_in, const int* in_sizes, int n_in,
                              void* d_out, int out_size, void* d_ws, size_t ws_size,
                              hipStream_t stream) {
    (void)in_sizes; (void)n_in; (void)out_size; (void)ws_size;
    const float* x  = (const float*)d_in[0];
    const int*   ei = (const int*)d_in[1];
    const int*   bt = (const int*)d_in[2];
    const float* W1 = (const float*)d_in[3];
    const float* b1 = (const float*)d_in[4];
    const float* W2 = (const float*)d_in[5];
    const float* b2 = (const float*)d_in[6];
    const float* W3 = (const float*)d_in[7];
    const float* b3 = (const float*)d_in[8];
    float* out = (float*)d_out;
    char* ws = (char*)d_ws;

    size_t o = 0;
    auto alloc = [&](size_t bytes) { size_t r = o; o = (o + bytes + 511) & ~(size_t)511; return r; };
    // zeroed region: deg + pool + cnt (one memset)
    int*    deg  = (int*)(ws + alloc((size_t)NN * 4));
    float*  pool = (float*)(ws + alloc((size_t)(NG * DD + NG) * 4));
    float*  cnt  = pool + NG * DD;
    size_t zbytes = o;
    float*  dinv = (float*)(ws + alloc((size_t)NN * 4));
    int*    rp   = (int*)(ws + alloc((size_t)(NN + 1) * 4));
    int*    bs   = (int*)(ws + alloc(256 * 4));
    int*    rank = (int*)(ws + alloc((size_t)NE * 4));
    ushort* col  = (ushort*)(ws + alloc((size_t)(NE + 8 * NN) * 2));  // padded CSR
    short*  wpk  = (short*)(ws + alloc((size_t)3 * 32768 * 2));
    ushort* hsT  = (ushort*)(ws + alloc((size_t)(NN + 1) * DD * 2)); // +1 zero row
    ushort* hsA  = (ushort*)(ws + alloc((size_t)NN * DD * 2));
    float*  F    = (float*)(ws + alloc((size_t)NN * DD * 4));

    const int* srcv = ei;        // edge_index[0]
    const int* dstv = ei + NE;   // edge_index[1]

    hipMemsetAsync(ws, 0, zbytes, stream);

    k_hist_wpack<<<2368, 256, 0, stream>>>(dstv, deg, rank, W1, W2, W3, wpk);
    k_scan1<<<196, 256, 0, stream>>>(deg, dinv, rp, bs);
    k_scan23<<<196, 256, 0, stream>>>(rp, bs, deg, col, hsT);
    k_scatter_xcd<<<((NE + 1023) / 1024) * 8, 256, 0, stream>>>(srcv, dstv, rank, rp, col);

    const dim3 gG((NN + 127) / 128, 2);   // 391 x 2
    k_gemm_mfma<1><<<gG, 256, 0, stream>>>(x, wpk, dinv, hsT);
    k_agg<1, 0><<<12500, 256, 0, stream>>>(hsT, col, rp, dinv, b1, hsA);
    k_gemm_mfma<0><<<gG, 256, 0, stream>>>(hsA, wpk + 32768, dinv, hsT);
    k_agg<1, 0><<<12500, 256, 0, stream>>>(hsT, col, rp, dinv, b2, hsA);
    k_gemm_mfma<0><<<gG, 256, 0, stream>>>(hsA, wpk + 65536, dinv, hsT);
    k_agg<0, 1><<<12500, 256, 0, stream>>>(hsT, col, rp, dinv, b3, F);

    k_pool<<<(NN + 63) / 64, 128, 0, stream>>>(F, bt, pool, cnt);
    k_final<<<(NG * DD) / 256, 256, 0, stream>>>(pool, cnt, out);
}